// Round 4
// baseline (361.705 us; speedup 1.0000x reference)
//
#include <hip/hip_runtime.h>
#include <hip/hip_bf16.h>

#define N 384
#define HIDN 128
#define NHD 8
#define DHD 16
#define NRB 64
#define CUTF 10.0f

// ws layout (float slots)
#define WS_V 0
#define WS_KP (WS_V + N*HIDN)                  // fp32 N*8*128
#define WS_QPB (WS_KP + N*NHD*HIDN)            // bf16 N*8*128 shorts
#define WS_GATE (WS_QPB + N*NHD*HIDN/2)
#define WS_SCORES (WS_GATE + N*NHD)

typedef short bf16x8 __attribute__((ext_vector_type(8)));
typedef float floatx4 __attribute__((ext_vector_type(4)));
#define MFMA16(a, b, c) __builtin_amdgcn_mfma_f32_16x16x32_bf16(a, b, c, 0, 0, 0)

__device__ __forceinline__ float siluf(float x) { return x / (1.0f + __expf(-x)); }
__device__ __forceinline__ float silu_fast(float x) {
    return x * __builtin_amdgcn_rcpf(1.0f + __expf(-x));
}
__device__ __forceinline__ short f2bf(float f) {
    unsigned int b = __float_as_uint(f);
    unsigned int r = (b + 0x7fffu + ((b >> 16) & 1u)) >> 16;
    return (short)r;
}
__device__ __forceinline__ float bf2f(short s) {
    return __uint_as_float(((unsigned int)(unsigned short)s) << 16);
}
__device__ __forceinline__ unsigned int pk_bf16(float a, float b) {
    union { __hip_bfloat162 h; unsigned int u; } cv;
    cv.h = __float22bfloat162_rn(make_float2(a, b));
    return cv.u;
}
__device__ __forceinline__ float wave_sum(float v) {
    for (int o = 32; o; o >>= 1) v += __shfl_down(v, o, 64);
    return v;
}

// K1: fused qkv + Qp(bf16)/Kp(fp32) + gates
__global__ __launch_bounds__(128) void k_pre(const float* __restrict__ ef,
    const float* __restrict__ wq, const float* __restrict__ wk, const float* __restrict__ wv,
    const float* __restrict__ aw1,
    const float* __restrict__ gw1, const float* __restrict__ gb1,
    const float* __restrict__ gw2, const float* __restrict__ gb2,
    float* __restrict__ v, unsigned short* __restrict__ Qpb,
    float* __restrict__ Kp, float* __restrict__ gates) {
    __shared__ float sE[HIDN], sQ[HIDN], sK[HIDN], sV[HIDN];
    __shared__ float sRed[2];
    int i = blockIdx.x, t = threadIdx.x;
    sE[t] = ef[i * HIDN + t];
    __syncthreads();
    float aq = 0.f, ak = 0.f, av = 0.f;
#pragma unroll 8
    for (int c = 0; c < HIDN; c++) {
        float e = sE[c];
        aq += e * wq[c * HIDN + t];
        ak += e * wk[c * HIDN + t];
        av += e * wv[c * HIDN + t];
    }
    v[i * HIDN + t] = av;
    sQ[t] = aq; sK[t] = ak; sV[t] = av;
    __syncthreads();
    for (int h = 0; h < NHD; h++) {
        float accq = 0.f, acck = 0.f;
#pragma unroll
        for (int d = 0; d < DHD; d++) {
            accq += sQ[h * DHD + d] * aw1[d * HIDN + t];
            acck += sK[h * DHD + d] * aw1[(DHD + d) * HIDN + t];
        }
        Qpb[(i * NHD + h) * HIDN + t] = (unsigned short)f2bf(accq);
        Kp[(i * NHD + h) * HIDN + t] = acck;
        float tt = gb1[t];
#pragma unroll
        for (int d = 0; d < DHD; d++) tt += sV[h * DHD + d] * gw1[d * HIDN + t];
        float contrib = siluf(tt) * gw2[t];
        float s = wave_sum(contrib);
        if ((t & 63) == 0) sRed[t >> 6] = s;
        __syncthreads();
        if (t == 0) gates[i * NHD + h] = 1.0f / (1.0f + __expf(-(sRed[0] + sRed[1] + gb2[0])));
        __syncthreads();
    }
}

// ---------------- K2: MFMA scores, 512 thr, wave==head, LDS-resident W2 ----------------
#define OFF_W2T  0       // 128 rows x 256B, granule-swizzled g^(n&15)   = 32768
#define OFF_W1RT 32768   // 128 rows x 128B, swizzled g^(n&7)            = 16384
#define OFF_W3T  49152   // bf16 [h][c]                                  = 2048
#define OFF_B1   51200   // f32 x128
#define OFF_W1D  51712
#define OFF_B2   52224
#define OFF_AB3  52736   // 32
#define OFF_SDD  52768   // 16 f32 dot
#define OFF_RBF  52832   // 16 rows x 128B, swizzled g^(j&7)             = 2048
#define OFF_R    54880   // 16 rows x 512B f32, swizzled g^j             = 8192
#define SMEM_SZ  63072

__global__ __launch_bounds__(512, 4) void k_scores_mfma(
    const float* __restrict__ coords, const float* __restrict__ mask,
    const float* __restrict__ centers, const float* __restrict__ widths,
    const float* __restrict__ aw1, const float* __restrict__ ab1,
    const float* __restrict__ aw2, const float* __restrict__ ab2,
    const float* __restrict__ aw3, const float* __restrict__ ab3,
    const unsigned short* __restrict__ Qpb, const float* __restrict__ Kp,
    float* __restrict__ scores) {
    __shared__ __align__(16) char smem[SMEM_SZ];
    const int t = threadIdx.x;
    const int lane = t & 63;
    const int w = t >> 6;          // wave id == head id, 0..7
    const int l15 = lane & 15;
    const int quad = lane >> 4;
    const int i = blockIdx.y;
    const int jb = blockIdx.x * 128;

    // ---- staging (once per block) ----
    // W2T[n][k] bf16, pairs along k; phys granule = (k/8) ^ (n&15)
    for (int idx = t; idx < 8192; idx += 512) {
        int k2 = (idx & 63) * 2, n = idx >> 6;
        unsigned int p = pk_bf16(aw2[k2 * HIDN + n], aw2[(k2 + 1) * HIDN + n]);
        *(unsigned int*)(smem + OFF_W2T + n * 256 + (((k2 >> 3) ^ (n & 15)) << 4) + (k2 & 7) * 2) = p;
    }
    // W1RT[n][r] bf16; phys granule = (r/8) ^ (n&7)
    for (int idx = t; idx < 4096; idx += 512) {
        int r2 = (idx & 31) * 2, n = idx >> 5;
        unsigned int p = pk_bf16(aw1[(32 + r2) * HIDN + n], aw1[(33 + r2) * HIDN + n]);
        *(unsigned int*)(smem + OFF_W1RT + n * 128 + (((r2 >> 3) ^ (n & 7)) << 4) + (r2 & 7) * 2) = p;
    }
    for (int idx = t; idx < HIDN * NHD; idx += 512) {
        int c = idx >> 3, h = idx & 7;
        *(short*)(smem + OFF_W3T + (h * 128 + c) * 2) = f2bf(aw3[idx]);
    }
    if (t < 128) {
        *(float*)(smem + OFF_B1 + t * 4) = ab1[t];
        *(float*)(smem + OFF_W1D + t * 4) = aw1[96 * HIDN + t];
        *(float*)(smem + OFF_B2 + t * 4) = ab2[t];
    }
    if (t < 8) *(float*)(smem + OFF_AB3 + t * 4) = ab3[t];
    // per-wave Qp fragments (head w), bf16, resident in regs
    bf16x8 qpf[4];
#pragma unroll
    for (int f = 0; f < 4; f++)
        qpf[f] = *(const bf16x8*)(Qpb + ((size_t)i * NHD + w) * HIDN + f * 32 + quad * 8);
    const float cix = coords[i * 3], ciy = coords[i * 3 + 1], ciz = coords[i * 3 + 2];
    __syncthreads();

    for (int ch = 0; ch < 8; ch++) {
        const int j0 = jb + ch * 16;
        // (a) rbf (all 512 threads: r = t&63, j = (t>>6) + 8p) + dot
        {
            int r = t & 63, jj = t >> 6;
            float cr = centers[r], rw = widths[r];
#pragma unroll
            for (int p = 0; p < 2; p++) {
                int j = jj + p * 8;
                int jg = j0 + j;
                float jx = coords[jg * 3], jy = coords[jg * 3 + 1], jz = coords[jg * 3 + 2];
                float dx = cix - jx, dy = ciy - jy, dz = ciz - jz;
                float dist = sqrtf(dx * dx + dy * dy + dz * dz) + 1e-8f;
                dist = fminf(fmaxf(dist, 1e-8f), 1e8f);
                float dd = dist - cr;
                float val = (dist <= CUTF) ? __expf(-rw * dd * dd) : 0.0f;
                *(short*)(smem + OFF_RBF + j * 128 + (((r >> 3) ^ (j & 7)) << 4) + (r & 7) * 2) = f2bf(val);
            }
            if (t < 16) {
                int jg = j0 + t;
                float jx = coords[jg * 3], jy = coords[jg * 3 + 1], jz = coords[jg * 3 + 2];
                float dot = fminf(fmaxf(cix * jx + ciy * jy + ciz * jz, -1e8f), 1e8f);
                *(float*)(smem + OFF_SDD + t * 4) = dot;
            }
        }
        __syncthreads();
        // (b) R = b1 + rbf@W1r + dot*w1d; wave w does col-tile ct=w
        {
            bf16x8 ra0 = *(const bf16x8*)(smem + OFF_RBF + l15 * 128 + (((quad) ^ (l15 & 7)) << 4));
            bf16x8 ra1 = *(const bf16x8*)(smem + OFF_RBF + l15 * 128 + (((quad + 4) ^ (l15 & 7)) << 4));
            int n = w * 16 + l15;
            bf16x8 b0 = *(const bf16x8*)(smem + OFF_W1RT + n * 128 + (((quad) ^ (n & 7)) << 4));
            bf16x8 b1 = *(const bf16x8*)(smem + OFF_W1RT + n * 128 + (((quad + 4) ^ (n & 7)) << 4));
            floatx4 acc = {0.f, 0.f, 0.f, 0.f};
            acc = MFMA16(ra0, b0, acc);
            acc = MFMA16(ra1, b1, acc);
            float b1v = *(const float*)(smem + OFF_B1 + n * 4);
            float w1dv = *(const float*)(smem + OFF_W1D + n * 4);
            int gc = n >> 2;
#pragma unroll
            for (int r = 0; r < 4; r++) {
                int j = quad * 4 + r;
                float dotv = *(const float*)(smem + OFF_SDD + j * 4);
                *(float*)(smem + OFF_R + j * 512 + ((gc ^ j) << 4) + (n & 3) * 4) = acc[r] + b1v + dotv * w1dv;
            }
        }
        __syncthreads();
        // (c) strip: head w, rows j0..j0+15; A built in-register
        {
            const float* kpr = Kp + ((size_t)(j0 + l15) * NHD + w) * HIDN;
            bf16x8 A[4];
#pragma unroll
            for (int f = 0; f < 4; f++) {
                int c8 = f * 32 + quad * 8;
                float4 kp0 = *(const float4*)(kpr + c8);
                float4 kp1 = *(const float4*)(kpr + c8 + 4);
                int g0 = f * 8 + quad * 2;
                float4 r0 = *(const float4*)(smem + OFF_R + l15 * 512 + (((g0) ^ l15) << 4));
                float4 r1 = *(const float4*)(smem + OFF_R + l15 * 512 + (((g0 + 1) ^ l15) << 4));
                float x0 = silu_fast(kp0.x + bf2f(qpf[f][0]) + r0.x);
                float x1 = silu_fast(kp0.y + bf2f(qpf[f][1]) + r0.y);
                float x2 = silu_fast(kp0.z + bf2f(qpf[f][2]) + r0.z);
                float x3 = silu_fast(kp0.w + bf2f(qpf[f][3]) + r0.w);
                float x4 = silu_fast(kp1.x + bf2f(qpf[f][4]) + r1.x);
                float x5 = silu_fast(kp1.y + bf2f(qpf[f][5]) + r1.y);
                float x6 = silu_fast(kp1.z + bf2f(qpf[f][6]) + r1.z);
                float x7 = silu_fast(kp1.w + bf2f(qpf[f][7]) + r1.w);
                union { int4 i4; bf16x8 v; } u;
                u.i4.x = (int)pk_bf16(x0, x1);
                u.i4.y = (int)pk_bf16(x2, x3);
                u.i4.z = (int)pk_bf16(x4, x5);
                u.i4.w = (int)pk_bf16(x6, x7);
                A[f] = u.v;
            }
            float part[4] = {0.f, 0.f, 0.f, 0.f};
#pragma unroll
            for (int ct = 0; ct < 8; ct++) {
                const char* wb = smem + OFF_W2T + (ct * 16 + l15) * 256;
                bf16x8 b0 = *(const bf16x8*)(wb + (((quad) ^ l15) << 4));
                bf16x8 b1 = *(const bf16x8*)(wb + (((quad + 4) ^ l15) << 4));
                bf16x8 b2 = *(const bf16x8*)(wb + (((quad + 8) ^ l15) << 4));
                bf16x8 b3 = *(const bf16x8*)(wb + (((quad + 12) ^ l15) << 4));
                floatx4 acc = {0.f, 0.f, 0.f, 0.f};
                acc = MFMA16(A[0], b0, acc);
                acc = MFMA16(A[1], b1, acc);
                acc = MFMA16(A[2], b2, acc);
                acc = MFMA16(A[3], b3, acc);
                int c = ct * 16 + l15;
                float b2v = *(const float*)(smem + OFF_B2 + c * 4);
                float w3v = bf2f(*(const short*)(smem + OFF_W3T + (w * 128 + c) * 2));
#pragma unroll
                for (int r = 0; r < 4; r++)
                    part[r] += silu_fast(acc[r] + b2v) * w3v;
            }
#pragma unroll
            for (int off = 1; off < 16; off <<= 1) {
#pragma unroll
                for (int r = 0; r < 4; r++) part[r] += __shfl_xor(part[r], off, 64);
            }
            if (l15 == 0) {
                float ab3v = *(const float*)(smem + OFF_AB3 + w * 4);
#pragma unroll
                for (int r = 0; r < 4; r++) {
                    int j = quad * 4 + r;
                    float s = part[r] + ab3v + mask[(size_t)i * N + j0 + j];
                    s = fminf(fmaxf(s, -1e9f), 1e9f);
                    scores[((size_t)w * N + i) * N + j0 + j] = s;
                }
            }
        }
        __syncthreads();
    }
}

// K3: fused softmax + attn@V + coords + wo/LN output. 1 block per i.
__global__ __launch_bounds__(256) void k_attn_out(
    const float* __restrict__ scores, const float* __restrict__ v,
    const float* __restrict__ gates, const float* __restrict__ coords,
    const float* __restrict__ ef, const float* __restrict__ wo,
    const float* __restrict__ bo, const float* __restrict__ lng,
    const float* __restrict__ lnb, float* __restrict__ out) {
    __shared__ float sA[4][N];
    __shared__ float sCrd[N * 3];
    __shared__ float sC[NHD][3];
    __shared__ float sUpd[HIDN];
    __shared__ float sYp[2][HIDN];
    __shared__ float sR[2], sR2[2];
    int i = blockIdx.x, t = threadIdx.x, w = t >> 6, lane = t & 63;
    for (int idx = t; idx < N * 3; idx += 256) sCrd[idx] = coords[idx];
    float cix = coords[i * 3], ciy = coords[i * 3 + 1], ciz = coords[i * 3 + 2];
    __syncthreads();
    for (int hh = 0; hh < 2; hh++) {
        int h = hh * 4 + w;
        const float* srow = scores + ((size_t)h * N + i) * N;
        float s[6];
#pragma unroll
        for (int p = 0; p < 6; p++) s[p] = srow[lane + 64 * p];
        float m = s[0];
#pragma unroll
        for (int p = 1; p < 6; p++) m = fmaxf(m, s[p]);
        for (int off = 1; off < 64; off <<= 1) m = fmaxf(m, __shfl_xor(m, off, 64));
        float e[6], sum = 0.f;
#pragma unroll
        for (int p = 0; p < 6; p++) { e[p] = __expf(s[p] - m); sum += e[p]; }
        for (int off = 1; off < 64; off <<= 1) sum += __shfl_xor(sum, off, 64);
        float inv = 1.0f / sum;
#pragma unroll
        for (int p = 0; p < 6; p++) sA[w][lane + 64 * p] = e[p] * inv;
        __syncthreads();
        int d4 = lane & 3, grp = lane >> 2;
        float4 f4 = {0.f, 0.f, 0.f, 0.f};
        for (int j = grp; j < N; j += 16) {
            float a = sA[w][j];
            float4 vv = *(const float4*)(v + j * HIDN + h * DHD + d4 * 4);
            f4.x += a * vv.x; f4.y += a * vv.y; f4.z += a * vv.z; f4.w += a * vv.w;
        }
#pragma unroll
        for (int off = 4; off < 64; off <<= 1) {
            f4.x += __shfl_xor(f4.x, off, 64);
            f4.y += __shfl_xor(f4.y, off, 64);
            f4.z += __shfl_xor(f4.z, off, 64);
            f4.w += __shfl_xor(f4.w, off, 64);
        }
        if (lane < 4) *(float4*)(sUpd + h * DHD + lane * 4) = f4;
        float cx = 0.f, cy = 0.f, cz = 0.f;
#pragma unroll
        for (int p = 0; p < 6; p++) {
            int j = lane + 64 * p;
            float a = sA[w][j];
            cx += a * (cix - sCrd[j * 3]);
            cy += a * (ciy - sCrd[j * 3 + 1]);
            cz += a * (ciz - sCrd[j * 3 + 2]);
        }
        for (int off = 1; off < 64; off <<= 1) {
            cx += __shfl_xor(cx, off, 64);
            cy += __shfl_xor(cy, off, 64);
            cz += __shfl_xor(cz, off, 64);
        }
        if (lane == 0) {
            float g = gates[i * NHD + h] * (1.0f / NHD);
            sC[h][0] = g * cx; sC[h][1] = g * cy; sC[h][2] = g * cz;
        }
        __syncthreads();
    }
    // Phase B: y = ef + upd@wo + bo, LayerNorm (split-k over 2 halves)
    {
        int c = t & 127, half = t >> 7;
        float acc = 0.f;
#pragma unroll 8
        for (int cp = half * 64; cp < half * 64 + 64; cp++)
            acc += sUpd[cp] * wo[cp * HIDN + c];
        sYp[half][c] = acc;
    }
    __syncthreads();
    float y = 0.f, dv = 0.f;
    if (t < 128) {
        y = ef[i * HIDN + t] + bo[t] + sYp[0][t] + sYp[1][t];
        float s = wave_sum(y);
        if ((t & 63) == 0) sR[t >> 6] = s;
    }
    __syncthreads();
    if (t < 128) {
        float mu = (sR[0] + sR[1]) * (1.0f / HIDN);
        dv = y - mu;
        float s2 = wave_sum(dv * dv);
        if ((t & 63) == 0) sR2[t >> 6] = s2;
    }
    __syncthreads();
    if (t < 128) {
        float var = (sR2[0] + sR2[1]) * (1.0f / HIDN);
        out[i * HIDN + t] = dv * rsqrtf(var + 1e-5f) * lng[t] + lnb[t];
    }
    if (t < 3) {
        float acc = coords[i * 3 + t];
#pragma unroll
        for (int h = 0; h < NHD; h++) acc += sC[h][t];
        out[N * HIDN + i * 3 + t] = acc;
    }
}

extern "C" void kernel_launch(void* const* d_in, const int* in_sizes, int n_in,
                              void* d_out, int out_size, void* d_ws, size_t ws_size,
                              hipStream_t stream) {
    const float* ef      = (const float*)d_in[0];
    const float* coords  = (const float*)d_in[1];
    const float* mask    = (const float*)d_in[2];
    const float* wq      = (const float*)d_in[3];
    const float* wk      = (const float*)d_in[4];
    const float* wv      = (const float*)d_in[5];
    const float* centers = (const float*)d_in[6];
    const float* widths  = (const float*)d_in[7];
    const float* aw1     = (const float*)d_in[8];
    const float* ab1     = (const float*)d_in[9];
    const float* aw2     = (const float*)d_in[10];
    const float* ab2     = (const float*)d_in[11];
    const float* aw3     = (const float*)d_in[12];
    const float* ab3     = (const float*)d_in[13];
    const float* gw1     = (const float*)d_in[14];
    const float* gb1     = (const float*)d_in[15];
    const float* gw2     = (const float*)d_in[16];
    const float* gb2     = (const float*)d_in[17];
    const float* wo      = (const float*)d_in[18];
    const float* bo      = (const float*)d_in[19];
    const float* lng     = (const float*)d_in[20];
    const float* lnb     = (const float*)d_in[21];
    float* ws = (float*)d_ws;
    float* v      = ws + WS_V;
    float* Kp     = ws + WS_KP;
    unsigned short* Qpb = (unsigned short*)(ws + WS_QPB);
    float* gates  = ws + WS_GATE;
    float* scores = ws + WS_SCORES;
    float* out = (float*)d_out;

    k_pre<<<N, 128, 0, stream>>>(ef, wq, wk, wv, aw1, gw1, gb1, gw2, gb2, v, Qpb, Kp, gates);
    k_scores_mfma<<<dim3(3, N), 512, 0, stream>>>(
        coords, mask, centers, widths, aw1, ab1, aw2, ab2, aw3, ab3, Qpb, Kp, scores);
    k_attn_out<<<N, 256, 0, stream>>>(scores, v, gates, coords, ef, wo, bo, lng, lnb, out);
}